// Round 8
// baseline (322.214 us; speedup 1.0000x reference)
//
#include <hip/hip_runtime.h>

// NarrativeClassificationLoss — v11b: fused single-pass main, 4-row MLP.
// (identical to v11; R11 bench failure was infra — container died twice,
//  kernel never ran. Resubmitting for measurement.)
// R10 post-mortem of v10: cooperative launch silently no-ops under the
// harness's graph capture (absmax == |loss| => output stayed zero).
// Plain dispatches only. Kept from v10: the verified fused phase-A math
// (narrative accumulators folded into the sub loop on even lanes; the
// sub loop already loads nlog/nlab[r,g] for hier => the separate 16MB
// narrative pass was pure waste).
// New vs v9: v9's main was VGPR=40 -> ~one row of loads in flight,
// explaining the latency-bound plateau (2.6TB/s logical, VALU 27%,
// occupancy-insensitive). v11 batches 4 rows of loads into registers
// with STATIC indices (~40 VGPR in flight) before computing, under
// launch_bounds(256,4): 128-VGPR cap, ~85 needed -> no pinch, no spill
// (v3/v7/v8 rule).
// Zero atomics, exclusive per-block tables, 3 dispatches, no memset.
//
// B=16384, N_NARR=128, N_SUB=1024, K=8, GAMMA=2, weights (1,1,0.5).

#define BDIM 256
#define NROWS 16384
#define NNARR 128
#define NSUB 1024
#define RPB 16
#define NBLOCKS (NROWS / RPB)              // 1024

// per-block table layout (floats)
#define WS_AN    0      // [128]  sum_b y*sp(-x)            (narrative)
#define WS_CN    128    // [128]  sum_b (1-y)*sp(x)
#define WS_NSUM  256    // [128]  col sums of narrative labels
#define WS_AS    384    // [1024] sum_b pos*y*sp(-x)        (subnarrative)
#define WS_CS    1408   // [1024] sum_b pos*(1-y)*sp(x)
#define WS_SSUM  2432   // [1024] col sums of sub labels
#define WS_FN    3456   // focal narrative sum
#define WS_FS    3457   // focal subnarrative sum
#define WS_HIER  3458   // hierarchy sum
#define WS_FLOATS 3459
#define CSTRIDE  3472   // table stride in floats (16B aligned)

#define NCHUNK 16                          // reduce fan-in groups
#define TPG (NBLOCKS / NCHUNK)             // 64 tables per group

__device__ __forceinline__ void bce_pieces(float x, float& sp_p, float& sp_m, float& sig) {
    float a = fabsf(x);
    float e = __expf(-a);              // exp(-|x|) in (0,1]
    float l = __logf(1.0f + e);        // ~log1p(e); err ~1e-7, fine after /2M
    sp_p = fmaxf(x, 0.0f) + l;
    sp_m = sp_p - x;
    float inv = __builtin_amdgcn_rcpf(1.0f + e);
    sig = (x >= 0.0f) ? inv : e * inv;
}

// one row's worth of work for this thread (sub quad 4t..4t+3, narr col t>>1)
__device__ __forceinline__ void row_accum(
    const float4 xs, const int4 ys, float nx, float posv, int t,
    float As[4], float Cs[4], float ss[4],
    float& An, float& Cn, float& ns, float& fn, float& fs, float& hier)
{
    float nsp_p, nsp_m, nsig;
    bce_pieces(nx, nsp_p, nsp_m, nsig);

    const float xv[4] = {xs.x, xs.y, xs.z, xs.w};
    const float yv[4] = {(float)ys.x, (float)ys.y, (float)ys.z, (float)ys.w};
    float mymax = 0.0f;
    #pragma unroll
    for (int k = 0; k < 4; ++k) {
        float sp_p, sp_m, sig;
        bce_pieces(xv[k], sp_p, sp_m, sig);
        float y = yv[k];
        As[k] += posv * y * sp_m;
        Cs[k] += posv * (1.0f - y) * sp_p;
        ss[k] += y;
        float om = 1.0f - sig;
        fs += om * om * y * (-sp_m);         // log_sigmoid(x) = -softplus(-x)
        mymax = fmaxf(mymax, sig);
    }
    // group of 8 sub cols = adjacent lane pair (t, t^1): same narr col
    float gmax = fmaxf(mymax, __shfl_xor(mymax, 1, 64));
    if ((t & 1) == 0) {
        hier += fmaxf(gmax - nsig, 0.0f) * posv;
        An += posv * nsp_m;
        Cn += (1.0f - posv) * nsp_p;
        ns += posv;
        float om = 1.0f - nsig;
        fn += om * om * posv * (-nsp_m);
    }
}

__global__ __launch_bounds__(BDIM, 4) void ncl_main(
    const float* __restrict__ nlog, const float* __restrict__ slog,
    const int*   __restrict__ nlab, const int*   __restrict__ slab,
    float* __restrict__ P)
{
    __shared__ float ssc[4][3];        // per-wave scalar partials

    const int t  = threadIdx.x;
    const int g  = t >> 1;
    const int r0 = blockIdx.x * RPB;
    float* const Pb = P + (size_t)blockIdx.x * CSTRIDE;

    float As[4] = {0,0,0,0}, Cs[4] = {0,0,0,0}, ss[4] = {0,0,0,0};
    float An = 0.f, Cn = 0.f, ns = 0.f, fn = 0.f, fs = 0.f, hier = 0.f;

    // 4 batches of 4 rows: all loads of a batch issued before any compute,
    // all register indices static (no scratch).
    #pragma unroll
    for (int ii = 0; ii < RPB / 4; ++ii) {
        float4 xs0, xs1, xs2, xs3;
        int4   ys0, ys1, ys2, ys3;
        float  nx0, nx1, nx2, nx3, pv0, pv1, pv2, pv3;
        {
            const int r = r0 + 4 * ii;
            const float* s0 = slog + (size_t)r * NSUB + 4 * t;
            const int*   l0 = slab + (size_t)r * NSUB + 4 * t;
            const float* n0 = nlog + (size_t)r * NNARR + g;
            const int*   m0 = nlab + (size_t)r * NNARR + g;
            xs0 = *(const float4*)(s0);
            xs1 = *(const float4*)(s0 + NSUB);
            xs2 = *(const float4*)(s0 + 2 * NSUB);
            xs3 = *(const float4*)(s0 + 3 * NSUB);
            ys0 = *(const int4*)(l0);
            ys1 = *(const int4*)(l0 + NSUB);
            ys2 = *(const int4*)(l0 + 2 * NSUB);
            ys3 = *(const int4*)(l0 + 3 * NSUB);
            nx0 = n0[0]; nx1 = n0[NNARR]; nx2 = n0[2 * NNARR]; nx3 = n0[3 * NNARR];
            pv0 = (float)m0[0];         pv1 = (float)m0[NNARR];
            pv2 = (float)m0[2 * NNARR]; pv3 = (float)m0[3 * NNARR];
        }
        row_accum(xs0, ys0, nx0, pv0, t, As, Cs, ss, An, Cn, ns, fn, fs, hier);
        row_accum(xs1, ys1, nx1, pv1, t, As, Cs, ss, An, Cn, ns, fn, fs, hier);
        row_accum(xs2, ys2, nx2, pv2, t, As, Cs, ss, An, Cn, ns, fn, fs, hier);
        row_accum(xs3, ys3, nx3, pv3, t, As, Cs, ss, An, Cn, ns, fn, fs, hier);
    }

    // exclusive per-block table: plain stores, no atomics.
    *(float4*)(Pb + WS_AS   + 4 * t) = make_float4(As[0], As[1], As[2], As[3]);
    *(float4*)(Pb + WS_CS   + 4 * t) = make_float4(Cs[0], Cs[1], Cs[2], Cs[3]);
    *(float4*)(Pb + WS_SSUM + 4 * t) = make_float4(ss[0], ss[1], ss[2], ss[3]);
    if ((t & 1) == 0) {
        Pb[WS_AN   + g] = An;
        Pb[WS_CN   + g] = Cn;
        Pb[WS_NSUM + g] = ns;
    }

    // scalar partials: wave shuffle reduce -> LDS -> thread 0
    #pragma unroll
    for (int off = 32; off; off >>= 1) {
        fn   += __shfl_down(fn,   off, 64);
        fs   += __shfl_down(fs,   off, 64);
        hier += __shfl_down(hier, off, 64);
    }
    if ((t & 63) == 0) {
        int w = t >> 6;
        ssc[w][0] = fn; ssc[w][1] = fs; ssc[w][2] = hier;
    }
    __syncthreads();
    if (t == 0) {
        float a = 0.f, b = 0.f, c = 0.f;
        #pragma unroll
        for (int w = 0; w < 4; ++w) { a += ssc[w][0]; b += ssc[w][1]; c += ssc[w][2]; }
        Pb[WS_FN] = a; Pb[WS_FS] = b; Pb[WS_HIER] = c;
    }
}

// reduce: block (e-chunk, g) sums TPG tables -> tmp[g]; fully coalesced.
__global__ __launch_bounds__(256) void ncl_reduce1(const float* __restrict__ P,
                                                   float* __restrict__ tmp)
{
    const int e = blockIdx.x * 256 + threadIdx.x;
    if (e >= WS_FLOATS) return;
    const int gg = blockIdx.y;
    const float* p = P + (size_t)gg * TPG * CSTRIDE + e;
    float s = 0.f;
    #pragma unroll 4
    for (int i = 0; i < TPG; ++i)
        s += p[(size_t)i * CSTRIDE];
    tmp[(size_t)gg * CSTRIDE + e] = s;
}

__global__ __launch_bounds__(1024) void ncl_finalize(const float* __restrict__ tmp,
                                                     float* __restrict__ out)
{
    __shared__ float sr[6][16];
    const int t = threadIdx.x;
    const float Bf = (float)NROWS;

    // sub column t, summed over the 16 chunk tables (coalesced across t)
    float As = 0.f, Csv = 0.f, ss = 0.f;
    #pragma unroll 4
    for (int gc = 0; gc < NCHUNK; ++gc) {
        const float* p = tmp + (size_t)gc * CSTRIDE;
        As  += p[WS_AS   + t];
        Csv += p[WS_CS   + t];
        ss  += p[WS_SSUM + t];
    }
    float spw = fminf(fmaxf((Bf - ss) / (ss + 1e-6f), 1.0f), 50.0f);
    float sub_part = spw * As + Csv;

    float narr_part = 0.f, valid_part = 0.f;
    if (t < NNARR) {
        float An = 0.f, Cn = 0.f, ns = 0.f;
        #pragma unroll 4
        for (int gc = 0; gc < NCHUNK; ++gc) {
            const float* p = tmp + (size_t)gc * CSTRIDE;
            An += p[WS_AN + t]; Cn += p[WS_CN + t]; ns += p[WS_NSUM + t];
        }
        float npw = fminf(fmaxf((Bf - ns) / (ns + 1e-6f), 1.0f), 50.0f);
        narr_part  = npw * An + Cn;
        valid_part = ns;
    }

    float fn_p = 0.f, fs_p = 0.f, hier_p = 0.f;
    if (t < NCHUNK) {
        const float* p = tmp + (size_t)t * CSTRIDE;
        fn_p = p[WS_FN]; fs_p = p[WS_FS]; hier_p = p[WS_HIER];
    }

    #pragma unroll
    for (int off = 32; off; off >>= 1) {
        sub_part   += __shfl_down(sub_part,   off, 64);
        narr_part  += __shfl_down(narr_part,  off, 64);
        valid_part += __shfl_down(valid_part, off, 64);
        fn_p       += __shfl_down(fn_p,       off, 64);
        fs_p       += __shfl_down(fs_p,       off, 64);
        hier_p     += __shfl_down(hier_p,     off, 64);
    }
    if ((t & 63) == 0) {
        int w = t >> 6;
        sr[0][w] = sub_part; sr[1][w] = narr_part; sr[2][w] = valid_part;
        sr[3][w] = fn_p;     sr[4][w] = fs_p;      sr[5][w] = hier_p;
    }
    __syncthreads();
    if (t == 0) {
        float sub_tot = 0.f, narr_tot = 0.f, valid = 0.f;
        float fn = 0.f, fs = 0.f, hier = 0.f;
        #pragma unroll
        for (int i = 0; i < 16; ++i) {
            sub_tot += sr[0][i]; narr_tot += sr[1][i]; valid += sr[2][i];
            fn += sr[3][i]; fs += sr[4][i]; hier += sr[5][i];
        }

        float narrative_loss = narr_tot / (Bf * (float)NNARR);
        float sub_loss = (valid > 0.0f) ? (sub_tot * (1.0f / 8.0f)) / fmaxf(valid, 1.0f) : 0.0f;
        float nf = fn / (Bf * (float)NNARR);
        float sf = fs / (Bf * (float)NSUB);
        float hier_loss = hier / Bf;

        out[0] = (narrative_loss - 0.1f * nf)
               + (sub_loss       - 0.1f * sf)
               + 0.5f * hier_loss;
    }
}

extern "C" void kernel_launch(void* const* d_in, const int* in_sizes, int n_in,
                              void* d_out, int out_size, void* d_ws, size_t ws_size,
                              hipStream_t stream) {
    const float* nlog = (const float*)d_in[0];
    const float* slog = (const float*)d_in[1];
    const int*   nlab = (const int*)d_in[2];
    const int*   slab = (const int*)d_in[3];
    float* P   = (float*)d_ws;                        // 1024 tables
    float* tmp = P + (size_t)NBLOCKS * CSTRIDE;       // 16 group tables
    float* out = (float*)d_out;

    // all workspace cells are exclusively written before read: no memset.
    ncl_main<<<NBLOCKS, BDIM, 0, stream>>>(nlog, slog, nlab, slab, P);
    dim3 gr((WS_FLOATS + 255) / 256, NCHUNK);
    ncl_reduce1<<<gr, 256, 0, stream>>>(P, tmp);
    ncl_finalize<<<1, 1024, 0, stream>>>(tmp, out);
}

// Round 9
// 181.558 us; speedup vs baseline: 1.7747x; 1.7747x over previous
//
#include <hip/hip_runtime.h>

// NarrativeClassificationLoss — v12: fused single-pass, spill-free.
// R11 post-mortem of v11 (202us main): VGPR_Count=64 + WRITE 358MB ->
// the backend targets MAX occupancy (8 waves/EU -> 64-VGPR budget; LDS
// is tiny) regardless of launch_bounds' min arg, and prefers spilling
// ~20 regs over dropping an occupancy level. v4's body fit in 64 (no
// spill); v11's manual 4-row batch needed ~85 -> spill. Fix: 
// __attribute__((amdgpu_waves_per_eu(4,4))) caps target occupancy at
// 4 waves/EU -> 128-VGPR budget, no spill pressure; plus NO manual
// batching (compiler schedules; v4/v9 proven).
// Kept from v11 (R8 PASSED, absmax 0.0 -> math verified): fused
// single-pass main — narrative accumulators fold into the sub loop on
// even lanes (the sub loop already loads nlog/nlab[r,g] for hier), so
// the separate 16MB narrative phase + its barrier are gone.
// Zero atomics, exclusive per-block tables, 3 dispatches, no memset.
//
// B=16384, N_NARR=128, N_SUB=1024, K=8, GAMMA=2, weights (1,1,0.5).

#define BDIM 256
#define NROWS 16384
#define NNARR 128
#define NSUB 1024
#define RPB 16
#define NBLOCKS (NROWS / RPB)              // 1024

// per-block table layout (floats)
#define WS_AN    0      // [128]  sum_b y*sp(-x)            (narrative)
#define WS_CN    128    // [128]  sum_b (1-y)*sp(x)
#define WS_NSUM  256    // [128]  col sums of narrative labels
#define WS_AS    384    // [1024] sum_b pos*y*sp(-x)        (subnarrative)
#define WS_CS    1408   // [1024] sum_b pos*(1-y)*sp(x)
#define WS_SSUM  2432   // [1024] col sums of sub labels
#define WS_FN    3456   // focal narrative sum
#define WS_FS    3457   // focal subnarrative sum
#define WS_HIER  3458   // hierarchy sum
#define WS_FLOATS 3459
#define CSTRIDE  3472   // table stride in floats (16B aligned)

#define NCHUNK 16                          // reduce fan-in groups
#define TPG (NBLOCKS / NCHUNK)             // 64 tables per group

__device__ __forceinline__ void bce_pieces(float x, float& sp_p, float& sp_m, float& sig) {
    float a = fabsf(x);
    float e = __expf(-a);              // exp(-|x|) in (0,1]
    float l = __logf(1.0f + e);        // ~log1p(e); err ~1e-7, fine after /2M
    sp_p = fmaxf(x, 0.0f) + l;
    sp_m = sp_p - x;
    float inv = __builtin_amdgcn_rcpf(1.0f + e);
    sig = (x >= 0.0f) ? inv : e * inv;
}

__global__ void __launch_bounds__(BDIM)
__attribute__((amdgpu_waves_per_eu(4, 4)))
ncl_main(
    const float* __restrict__ nlog, const float* __restrict__ slog,
    const int*   __restrict__ nlab, const int*   __restrict__ slab,
    float* __restrict__ P)
{
    __shared__ float ssc[4][3];        // per-wave scalar partials

    const int t  = threadIdx.x;
    const int g  = t >> 1;
    const int r0 = blockIdx.x * RPB;
    float* const Pb = P + (size_t)blockIdx.x * CSTRIDE;

    float As[4] = {0,0,0,0}, Cs[4] = {0,0,0,0}, ss[4] = {0,0,0,0};
    float An = 0.f, Cn = 0.f, ns = 0.f, fn = 0.f, fs = 0.f, hier = 0.f;

    const float* sp = slog + (size_t)r0 * NSUB + 4 * t;
    const int*   lp = slab + (size_t)r0 * NSUB + 4 * t;
    const float* np = nlog + (size_t)r0 * NNARR + g;
    const int*   mp = nlab + (size_t)r0 * NNARR + g;

    #pragma unroll 2
    for (int i = 0; i < RPB; ++i) {
        const float4 xs   = *(const float4*)(sp + (size_t)i * NSUB);
        const int4   ys   = *(const int4*)  (lp + (size_t)i * NSUB);
        const float  nx   = np[(size_t)i * NNARR];
        const float  posv = (float)mp[(size_t)i * NNARR];   // narr label == pos mask

        float nsp_p, nsp_m, nsig;
        bce_pieces(nx, nsp_p, nsp_m, nsig);

        const float xv[4] = {xs.x, xs.y, xs.z, xs.w};
        const float yv[4] = {(float)ys.x, (float)ys.y, (float)ys.z, (float)ys.w};
        float mymax = 0.0f;
        #pragma unroll
        for (int k = 0; k < 4; ++k) {
            float sp_p, sp_m, sig;
            bce_pieces(xv[k], sp_p, sp_m, sig);
            float y = yv[k];
            As[k] += posv * y * sp_m;
            Cs[k] += posv * (1.0f - y) * sp_p;
            ss[k] += y;
            float om = 1.0f - sig;
            fs += om * om * y * (-sp_m);     // log_sigmoid(x) = -softplus(-x)
            mymax = fmaxf(mymax, sig);
        }
        // group of 8 sub cols = adjacent lane pair (t, t^1): same narr col
        float gmax = fmaxf(mymax, __shfl_xor(mymax, 1, 64));
        if ((t & 1) == 0) {
            hier += fmaxf(gmax - nsig, 0.0f) * posv;
            An += posv * nsp_m;
            Cn += (1.0f - posv) * nsp_p;
            ns += posv;
            float om = 1.0f - nsig;
            fn += om * om * posv * (-nsp_m);
        }
    }

    // exclusive per-block table: plain stores, no atomics.
    *(float4*)(Pb + WS_AS   + 4 * t) = make_float4(As[0], As[1], As[2], As[3]);
    *(float4*)(Pb + WS_CS   + 4 * t) = make_float4(Cs[0], Cs[1], Cs[2], Cs[3]);
    *(float4*)(Pb + WS_SSUM + 4 * t) = make_float4(ss[0], ss[1], ss[2], ss[3]);
    if ((t & 1) == 0) {
        Pb[WS_AN   + g] = An;
        Pb[WS_CN   + g] = Cn;
        Pb[WS_NSUM + g] = ns;
    }

    // scalar partials: wave shuffle reduce -> LDS -> thread 0
    #pragma unroll
    for (int off = 32; off; off >>= 1) {
        fn   += __shfl_down(fn,   off, 64);
        fs   += __shfl_down(fs,   off, 64);
        hier += __shfl_down(hier, off, 64);
    }
    if ((t & 63) == 0) {
        int w = t >> 6;
        ssc[w][0] = fn; ssc[w][1] = fs; ssc[w][2] = hier;
    }
    __syncthreads();
    if (t == 0) {
        float a = 0.f, b = 0.f, c = 0.f;
        #pragma unroll
        for (int w = 0; w < 4; ++w) { a += ssc[w][0]; b += ssc[w][1]; c += ssc[w][2]; }
        Pb[WS_FN] = a; Pb[WS_FS] = b; Pb[WS_HIER] = c;
    }
}

// reduce: block (e-chunk, g) sums TPG tables -> tmp[g]; fully coalesced.
__global__ __launch_bounds__(256) void ncl_reduce1(const float* __restrict__ P,
                                                   float* __restrict__ tmp)
{
    const int e = blockIdx.x * 256 + threadIdx.x;
    if (e >= WS_FLOATS) return;
    const int gg = blockIdx.y;
    const float* p = P + (size_t)gg * TPG * CSTRIDE + e;
    float s = 0.f;
    #pragma unroll 4
    for (int i = 0; i < TPG; ++i)
        s += p[(size_t)i * CSTRIDE];
    tmp[(size_t)gg * CSTRIDE + e] = s;
}

__global__ __launch_bounds__(1024) void ncl_finalize(const float* __restrict__ tmp,
                                                     float* __restrict__ out)
{
    __shared__ float sr[6][16];
    const int t = threadIdx.x;
    const float Bf = (float)NROWS;

    // sub column t, summed over the 16 chunk tables (coalesced across t)
    float As = 0.f, Csv = 0.f, ss = 0.f;
    #pragma unroll 4
    for (int gc = 0; gc < NCHUNK; ++gc) {
        const float* p = tmp + (size_t)gc * CSTRIDE;
        As  += p[WS_AS   + t];
        Csv += p[WS_CS   + t];
        ss  += p[WS_SSUM + t];
    }
    float spw = fminf(fmaxf((Bf - ss) / (ss + 1e-6f), 1.0f), 50.0f);
    float sub_part = spw * As + Csv;

    float narr_part = 0.f, valid_part = 0.f;
    if (t < NNARR) {
        float An = 0.f, Cn = 0.f, ns = 0.f;
        #pragma unroll 4
        for (int gc = 0; gc < NCHUNK; ++gc) {
            const float* p = tmp + (size_t)gc * CSTRIDE;
            An += p[WS_AN + t]; Cn += p[WS_CN + t]; ns += p[WS_NSUM + t];
        }
        float npw = fminf(fmaxf((Bf - ns) / (ns + 1e-6f), 1.0f), 50.0f);
        narr_part  = npw * An + Cn;
        valid_part = ns;
    }

    float fn_p = 0.f, fs_p = 0.f, hier_p = 0.f;
    if (t < NCHUNK) {
        const float* p = tmp + (size_t)t * CSTRIDE;
        fn_p = p[WS_FN]; fs_p = p[WS_FS]; hier_p = p[WS_HIER];
    }

    #pragma unroll
    for (int off = 32; off; off >>= 1) {
        sub_part   += __shfl_down(sub_part,   off, 64);
        narr_part  += __shfl_down(narr_part,  off, 64);
        valid_part += __shfl_down(valid_part, off, 64);
        fn_p       += __shfl_down(fn_p,       off, 64);
        fs_p       += __shfl_down(fs_p,       off, 64);
        hier_p     += __shfl_down(hier_p,     off, 64);
    }
    if ((t & 63) == 0) {
        int w = t >> 6;
        sr[0][w] = sub_part; sr[1][w] = narr_part; sr[2][w] = valid_part;
        sr[3][w] = fn_p;     sr[4][w] = fs_p;      sr[5][w] = hier_p;
    }
    __syncthreads();
    if (t == 0) {
        float sub_tot = 0.f, narr_tot = 0.f, valid = 0.f;
        float fn = 0.f, fs = 0.f, hier = 0.f;
        #pragma unroll
        for (int i = 0; i < 16; ++i) {
            sub_tot += sr[0][i]; narr_tot += sr[1][i]; valid += sr[2][i];
            fn += sr[3][i]; fs += sr[4][i]; hier += sr[5][i];
        }

        float narrative_loss = narr_tot / (Bf * (float)NNARR);
        float sub_loss = (valid > 0.0f) ? (sub_tot * (1.0f / 8.0f)) / fmaxf(valid, 1.0f) : 0.0f;
        float nf = fn / (Bf * (float)NNARR);
        float sf = fs / (Bf * (float)NSUB);
        float hier_loss = hier / Bf;

        out[0] = (narrative_loss - 0.1f * nf)
               + (sub_loss       - 0.1f * sf)
               + 0.5f * hier_loss;
    }
}

extern "C" void kernel_launch(void* const* d_in, const int* in_sizes, int n_in,
                              void* d_out, int out_size, void* d_ws, size_t ws_size,
                              hipStream_t stream) {
    const float* nlog = (const float*)d_in[0];
    const float* slog = (const float*)d_in[1];
    const int*   nlab = (const int*)d_in[2];
    const int*   slab = (const int*)d_in[3];
    float* P   = (float*)d_ws;                        // 1024 tables
    float* tmp = P + (size_t)NBLOCKS * CSTRIDE;       // 16 group tables
    float* out = (float*)d_out;

    // all workspace cells are exclusively written before read: no memset.
    ncl_main<<<NBLOCKS, BDIM, 0, stream>>>(nlog, slog, nlab, slab, P);
    dim3 gr((WS_FLOATS + 255) / 256, NCHUNK);
    ncl_reduce1<<<gr, 256, 0, stream>>>(P, tmp);
    ncl_finalize<<<1, 1024, 0, stream>>>(tmp, out);
}